// Round 7
// baseline (122.922 us; speedup 1.0000x reference)
//
#include <hip/hip_runtime.h>

// LayerNormSubspace: out[b,s,h] = xhat[b,s,h] * (alpha[b,s,:] @ W)[h] + (alpha[b,s,:] @ b)[h]
// x: [4,8192,1024] f32, alpha: [4,8192,4] f32, W: [4,1024] f32, b: [4,1024] f32
// 32768 rows of HS=1024. Compulsory traffic 256.5 MiB -> 42.7us @ 6.29 TB/s.
//
// R6 -> R7: isolate the R6 confound (prefetch AND occupancy changed together).
// Keep prefetch-before-reduce software pipeline, but at BPI=2 / grid=2048 /
// 8 blocks/CU (launch_bounds(256,8)) so occupancy returns to R5's level.
// If flat: the 6.29 TB/s mixed R/W stream wall is the roofline.

constexpr int HS  = 1024;
constexpr int BPI = 2;  // rows per block-iteration

typedef float vfloat4 __attribute__((ext_vector_type(4)));

__device__ __forceinline__ float4 ld4(const float* p) {
    return *reinterpret_cast<const float4*>(p);
}

__device__ __forceinline__ void st4_nt(float* p, float a, float b, float c, float d) {
    vfloat4 v = {a, b, c, d};
    __builtin_nontemporal_store(v, reinterpret_cast<vfloat4*>(p));
}

// x += dpp_permute(x, CTRL), 0-fill for invalid source lanes (bound_ctrl=true)
template <int CTRL>
__device__ __forceinline__ float dpp_add(float x) {
    int y = __builtin_amdgcn_update_dpp(0, __float_as_int(x), CTRL, 0xf, 0xf, true);
    return x + __int_as_float(y);
}

// Full 64-lane sum; valid result lives in lane 63.
__device__ __forceinline__ float wave_sum_to_lane63(float x) {
    x = dpp_add<0x111>(x);  // row_shr:1
    x = dpp_add<0x112>(x);  // row_shr:2
    x = dpp_add<0x114>(x);  // row_shr:4
    x = dpp_add<0x118>(x);  // row_shr:8
    x = dpp_add<0x142>(x);  // row_bcast15
    x = dpp_add<0x143>(x);  // row_bcast31 -> full sum in lane 63
    return x;
}

#define SUMS(xv, s, ss)                                                        \
    float s  = (xv.x + xv.y) + (xv.z + xv.w);                                  \
    float ss = fmaf(xv.x, xv.x, fmaf(xv.y, xv.y, fmaf(xv.z, xv.z, xv.w * xv.w)));

#define EMIT(xv, av, mean, rstd, dst) do {                                     \
    float ew, eb, o0, o1, o2, o3;                                              \
    ew = fmaf(av.x, w0.x, fmaf(av.y, w1.x, fmaf(av.z, w2.x, av.w * w3.x)));    \
    eb = fmaf(av.x, b0.x, fmaf(av.y, b1.x, fmaf(av.z, b2.x, av.w * b3.x)));    \
    o0 = fmaf((xv.x - mean) * rstd, ew, eb);                                   \
    ew = fmaf(av.x, w0.y, fmaf(av.y, w1.y, fmaf(av.z, w2.y, av.w * w3.y)));    \
    eb = fmaf(av.x, b0.y, fmaf(av.y, b1.y, fmaf(av.z, b2.y, av.w * b3.y)));    \
    o1 = fmaf((xv.y - mean) * rstd, ew, eb);                                   \
    ew = fmaf(av.x, w0.z, fmaf(av.y, w1.z, fmaf(av.z, w2.z, av.w * w3.z)));    \
    eb = fmaf(av.x, b0.z, fmaf(av.y, b1.z, fmaf(av.z, b2.z, av.w * b3.z)));    \
    o2 = fmaf((xv.z - mean) * rstd, ew, eb);                                   \
    ew = fmaf(av.x, w0.w, fmaf(av.y, w1.w, fmaf(av.z, w2.w, av.w * w3.w)));    \
    eb = fmaf(av.x, b0.w, fmaf(av.y, b1.w, fmaf(av.z, b2.w, av.w * b3.w)));    \
    o3 = fmaf((xv.w - mean) * rstd, ew, eb);                                   \
    st4_nt(dst, o0, o1, o2, o3);                                               \
} while (0)

__global__ __launch_bounds__(256, 8) void lns_kernel(
    const float* __restrict__ x,
    const float* __restrict__ alpha,
    const float* __restrict__ W,
    const float* __restrict__ Bias,
    float* __restrict__ out,
    int nrows)
{
    const int t  = threadIdx.x;
    const int h4 = t * 4;

    // Row-invariant W/b in registers (32 VGPRs).
    const float4 w0 = ld4(W + 0 * HS + h4);
    const float4 w1 = ld4(W + 1 * HS + h4);
    const float4 w2 = ld4(W + 2 * HS + h4);
    const float4 w3 = ld4(W + 3 * HS + h4);
    const float4 b0 = ld4(Bias + 0 * HS + h4);
    const float4 b1 = ld4(Bias + 1 * HS + h4);
    const float4 b2 = ld4(Bias + 2 * HS + h4);
    const float4 b3 = ld4(Bias + 3 * HS + h4);

    // red[parity][wave] = {s0, ss0, s1, ss1}
    __shared__ vfloat4 red[2][4];

    const int wv     = t >> 6;
    const int stride = gridDim.x * BPI;
    const int iters  = nrows / stride;  // exact: 32768 / 4096 = 8
    int row          = blockIdx.x * BPI;

    // Prologue: load iteration 0.
    size_t base = (size_t)row * HS + h4;
    float4 xc0 = ld4(x + base);
    float4 xc1 = ld4(x + base + HS);
    float4 aA  = ld4(alpha + (size_t)row * 4);
    float4 aB  = ld4(alpha + (size_t)row * 4 + 4);

    for (int it = 0; it < iters; ++it, row += stride) {
        // Issue NEXT iteration's loads before the reduce/barrier/epilogue.
        float4 xn0, xn1, nA, nB;
        const bool more = (it + 1 < iters);
        if (more) {
            const size_t nb = (size_t)(row + stride) * HS + h4;
            xn0 = ld4(x + nb);
            xn1 = ld4(x + nb + HS);
            nA  = ld4(alpha + (size_t)(row + stride) * 4);
            nB  = ld4(alpha + (size_t)(row + stride) * 4 + 4);
        }

        SUMS(xc0, s0, ss0);
        SUMS(xc1, s1, ss1);

        s0  = wave_sum_to_lane63(s0);
        ss0 = wave_sum_to_lane63(ss0);
        s1  = wave_sum_to_lane63(s1);
        ss1 = wave_sum_to_lane63(ss1);

        const int p = it & 1;
        if ((t & 63) == 63) {
            vfloat4 v = {s0, ss0, s1, ss1};
            red[p][wv] = v;
        }
        __syncthreads();  // one barrier per 2 rows; parity buffer protects reuse

        const vfloat4 r0 = red[p][0];
        const vfloat4 r1 = red[p][1];
        const vfloat4 r2 = red[p][2];
        const vfloat4 r3 = red[p][3];
        s0  = (r0.x + r1.x) + (r2.x + r3.x);
        ss0 = (r0.y + r1.y) + (r2.y + r3.y);
        s1  = (r0.z + r1.z) + (r2.z + r3.z);
        ss1 = (r0.w + r1.w) + (r2.w + r3.w);

        const float mean0 = s0 * (1.0f / HS);
        const float rstd0 = rsqrtf(fmaf(-mean0, mean0, ss0 * (1.0f / HS)) + 1e-5f);
        const float mean1 = s1 * (1.0f / HS);
        const float rstd1 = rsqrtf(fmaf(-mean1, mean1, ss1 * (1.0f / HS)) + 1e-5f);

        base = (size_t)row * HS + h4;
        EMIT(xc0, aA, mean0, rstd0, out + base);
        EMIT(xc1, aB, mean1, rstd1, out + base + HS);

        xc0 = xn0; xc1 = xn1;
        aA = nA; aB = nB;
    }
}

extern "C" void kernel_launch(void* const* d_in, const int* in_sizes, int n_in,
                              void* d_out, int out_size, void* d_ws, size_t ws_size,
                              hipStream_t stream) {
    const float* x     = (const float*)d_in[0];
    const float* alpha = (const float*)d_in[1];
    const float* W     = (const float*)d_in[2];
    const float* Bias  = (const float*)d_in[3];
    float* out = (float*)d_out;

    const int nrows = in_sizes[0] / HS;  // 32768

    // 2048 blocks = 256 CUs x 8 blocks/CU; each block runs 8 iterations of
    // 2 rows. 32768 = 2048*2*8 exactly.
    const int grid = 2048;
    lns_kernel<<<grid, 256, 0, stream>>>(x, alpha, W, Bias, out, nrows);
}

// Round 8
// 47.452 us; speedup vs baseline: 2.5905x; 2.5905x over previous
//
#include <hip/hip_runtime.h>

// LayerNormSubspace: out[b,s,h] = xhat[b,s,h] * (alpha[b,s,:] @ W)[h] + (alpha[b,s,:] @ b)[h]
// x: [4,8192,1024] f32, alpha: [4,8192,4] f32, W: [4,1024] f32, b: [4,1024] f32
// 32768 rows of HS=1024. Compulsory traffic 256.5 MiB -> 42.7us @ 6.29 TB/s.
//
// R7 -> R8: R7's launch_bounds(256,8) capped VGPRs at 64 and the pipeline
// state spilled to scratch (WRITE_SIZE 134->385 MB, FETCH 67->185 MB, 2.7x
// slower). Same pipelined structure, launch_bounds(256,4) (128-VGPR cap) so
// the pipeline lives in registers. If the allocator lands <=64 VGPR we get
// the clean "pipeline + 8 blocks/CU" isolation; else >=R6 occupancy, no spill.
// R5 (no pipe, 32w/CU)=46.6us, R6 (pipe, 16w/CU)=46.2us, both ~93% of the
// 6.29 TB/s copy ceiling -- if R8 is flat too, that's the roofline.

constexpr int HS  = 1024;
constexpr int BPI = 2;  // rows per block-iteration

typedef float vfloat4 __attribute__((ext_vector_type(4)));

__device__ __forceinline__ float4 ld4(const float* p) {
    return *reinterpret_cast<const float4*>(p);
}

__device__ __forceinline__ void st4_nt(float* p, float a, float b, float c, float d) {
    vfloat4 v = {a, b, c, d};
    __builtin_nontemporal_store(v, reinterpret_cast<vfloat4*>(p));
}

// x += dpp_permute(x, CTRL), 0-fill for invalid source lanes (bound_ctrl=true)
template <int CTRL>
__device__ __forceinline__ float dpp_add(float x) {
    int y = __builtin_amdgcn_update_dpp(0, __float_as_int(x), CTRL, 0xf, 0xf, true);
    return x + __int_as_float(y);
}

// Full 64-lane sum; valid result lives in lane 63.
__device__ __forceinline__ float wave_sum_to_lane63(float x) {
    x = dpp_add<0x111>(x);  // row_shr:1
    x = dpp_add<0x112>(x);  // row_shr:2
    x = dpp_add<0x114>(x);  // row_shr:4
    x = dpp_add<0x118>(x);  // row_shr:8
    x = dpp_add<0x142>(x);  // row_bcast15
    x = dpp_add<0x143>(x);  // row_bcast31 -> full sum in lane 63
    return x;
}

#define SUMS(xv, s, ss)                                                        \
    float s  = (xv.x + xv.y) + (xv.z + xv.w);                                  \
    float ss = fmaf(xv.x, xv.x, fmaf(xv.y, xv.y, fmaf(xv.z, xv.z, xv.w * xv.w)));

#define EMIT(xv, av, mean, rstd, dst) do {                                     \
    float ew, eb, o0, o1, o2, o3;                                              \
    ew = fmaf(av.x, w0.x, fmaf(av.y, w1.x, fmaf(av.z, w2.x, av.w * w3.x)));    \
    eb = fmaf(av.x, b0.x, fmaf(av.y, b1.x, fmaf(av.z, b2.x, av.w * b3.x)));    \
    o0 = fmaf((xv.x - mean) * rstd, ew, eb);                                   \
    ew = fmaf(av.x, w0.y, fmaf(av.y, w1.y, fmaf(av.z, w2.y, av.w * w3.y)));    \
    eb = fmaf(av.x, b0.y, fmaf(av.y, b1.y, fmaf(av.z, b2.y, av.w * b3.y)));    \
    o1 = fmaf((xv.y - mean) * rstd, ew, eb);                                   \
    ew = fmaf(av.x, w0.z, fmaf(av.y, w1.z, fmaf(av.z, w2.z, av.w * w3.z)));    \
    eb = fmaf(av.x, b0.z, fmaf(av.y, b1.z, fmaf(av.z, b2.z, av.w * b3.z)));    \
    o2 = fmaf((xv.z - mean) * rstd, ew, eb);                                   \
    ew = fmaf(av.x, w0.w, fmaf(av.y, w1.w, fmaf(av.z, w2.w, av.w * w3.w)));    \
    eb = fmaf(av.x, b0.w, fmaf(av.y, b1.w, fmaf(av.z, b2.w, av.w * b3.w)));    \
    o3 = fmaf((xv.w - mean) * rstd, ew, eb);                                   \
    st4_nt(dst, o0, o1, o2, o3);                                               \
} while (0)

__global__ __launch_bounds__(256, 4) void lns_kernel(
    const float* __restrict__ x,
    const float* __restrict__ alpha,
    const float* __restrict__ W,
    const float* __restrict__ Bias,
    float* __restrict__ out,
    int nrows)
{
    const int t  = threadIdx.x;
    const int h4 = t * 4;

    // Row-invariant W/b in registers (32 VGPRs).
    const float4 w0 = ld4(W + 0 * HS + h4);
    const float4 w1 = ld4(W + 1 * HS + h4);
    const float4 w2 = ld4(W + 2 * HS + h4);
    const float4 w3 = ld4(W + 3 * HS + h4);
    const float4 b0 = ld4(Bias + 0 * HS + h4);
    const float4 b1 = ld4(Bias + 1 * HS + h4);
    const float4 b2 = ld4(Bias + 2 * HS + h4);
    const float4 b3 = ld4(Bias + 3 * HS + h4);

    // red[parity][wave] = {s0, ss0, s1, ss1}
    __shared__ vfloat4 red[2][4];

    const int wv     = t >> 6;
    const int stride = gridDim.x * BPI;
    const int iters  = nrows / stride;  // exact: 32768 / 4096 = 8
    int row          = blockIdx.x * BPI;

    // Prologue: load iteration 0.
    size_t base = (size_t)row * HS + h4;
    float4 xc0 = ld4(x + base);
    float4 xc1 = ld4(x + base + HS);
    float4 aA  = ld4(alpha + (size_t)row * 4);
    float4 aB  = ld4(alpha + (size_t)row * 4 + 4);

    for (int it = 0; it < iters; ++it, row += stride) {
        // Issue NEXT iteration's loads before the reduce/barrier/epilogue.
        float4 xn0, xn1, nA, nB;
        const bool more = (it + 1 < iters);
        if (more) {
            const size_t nb = (size_t)(row + stride) * HS + h4;
            xn0 = ld4(x + nb);
            xn1 = ld4(x + nb + HS);
            nA  = ld4(alpha + (size_t)(row + stride) * 4);
            nB  = ld4(alpha + (size_t)(row + stride) * 4 + 4);
        }

        SUMS(xc0, s0, ss0);
        SUMS(xc1, s1, ss1);

        s0  = wave_sum_to_lane63(s0);
        ss0 = wave_sum_to_lane63(ss0);
        s1  = wave_sum_to_lane63(s1);
        ss1 = wave_sum_to_lane63(ss1);

        const int p = it & 1;
        if ((t & 63) == 63) {
            vfloat4 v = {s0, ss0, s1, ss1};
            red[p][wv] = v;
        }
        __syncthreads();  // one barrier per 2 rows; parity buffer protects reuse

        const vfloat4 r0 = red[p][0];
        const vfloat4 r1 = red[p][1];
        const vfloat4 r2 = red[p][2];
        const vfloat4 r3 = red[p][3];
        s0  = (r0.x + r1.x) + (r2.x + r3.x);
        ss0 = (r0.y + r1.y) + (r2.y + r3.y);
        s1  = (r0.z + r1.z) + (r2.z + r3.z);
        ss1 = (r0.w + r1.w) + (r2.w + r3.w);

        const float mean0 = s0 * (1.0f / HS);
        const float rstd0 = rsqrtf(fmaf(-mean0, mean0, ss0 * (1.0f / HS)) + 1e-5f);
        const float mean1 = s1 * (1.0f / HS);
        const float rstd1 = rsqrtf(fmaf(-mean1, mean1, ss1 * (1.0f / HS)) + 1e-5f);

        base = (size_t)row * HS + h4;
        EMIT(xc0, aA, mean0, rstd0, out + base);
        EMIT(xc1, aB, mean1, rstd1, out + base + HS);

        xc0 = xn0; xc1 = xn1;
        aA = nA; aB = nB;
    }
}

extern "C" void kernel_launch(void* const* d_in, const int* in_sizes, int n_in,
                              void* d_out, int out_size, void* d_ws, size_t ws_size,
                              hipStream_t stream) {
    const float* x     = (const float*)d_in[0];
    const float* alpha = (const float*)d_in[1];
    const float* W     = (const float*)d_in[2];
    const float* Bias  = (const float*)d_in[3];
    float* out = (float*)d_out;

    const int nrows = in_sizes[0] / HS;  // 32768

    // 2048 blocks = 256 CUs x 8 blocks/CU target; each block runs 8
    // iterations of 2 rows. 32768 = 2048*2*8 exactly.
    const int grid = 2048;
    lns_kernel<<<grid, 256, 0, stream>>>(x, alpha, W, Bias, out, nrows);
}

// Round 9
// 46.357 us; speedup vs baseline: 2.6516x; 1.0236x over previous
//
#include <hip/hip_runtime.h>

// LayerNormSubspace: out[b,s,h] = xhat[b,s,h] * (alpha[b,s,:] @ W)[h] + (alpha[b,s,:] @ b)[h]
// x: [4,8192,1024] f32, alpha: [4,8192,4] f32, W: [4,1024] f32, b: [4,1024] f32
// 32768 rows of HS=1024. Compulsory traffic 256.5 MiB -> 42.7us @ 6.29 TB/s.
//
// R8 -> R9: restore the best-measured variant (R6: BPI=4, grid 1024,
// prefetch-before-reduce pipeline, DPP reduce, nt stores). Confound matrix
// complete: R5 (no pipe, 61% occ)=46.6, R6 (pipe, 31% occ)=46.2,
// R8 (pipe, 40% occ)=47.5 -- all ~90% of the 6.29 TB/s copy ceiling with
// VALU 21%, DS ~0, conflicts 0. Memory-fabric saturated; this is the final
// configuration.

constexpr int HS  = 1024;
constexpr int BPI = 4;  // rows per block-iteration

typedef float vfloat4 __attribute__((ext_vector_type(4)));

__device__ __forceinline__ float4 ld4(const float* p) {
    return *reinterpret_cast<const float4*>(p);
}

__device__ __forceinline__ void st4_nt(float* p, float a, float b, float c, float d) {
    vfloat4 v = {a, b, c, d};
    __builtin_nontemporal_store(v, reinterpret_cast<vfloat4*>(p));
}

// x += dpp_permute(x, CTRL), 0-fill for invalid source lanes (bound_ctrl=true)
template <int CTRL>
__device__ __forceinline__ float dpp_add(float x) {
    int y = __builtin_amdgcn_update_dpp(0, __float_as_int(x), CTRL, 0xf, 0xf, true);
    return x + __int_as_float(y);
}

// Full 64-lane sum; valid result lives in lane 63.
__device__ __forceinline__ float wave_sum_to_lane63(float x) {
    x = dpp_add<0x111>(x);  // row_shr:1
    x = dpp_add<0x112>(x);  // row_shr:2
    x = dpp_add<0x114>(x);  // row_shr:4
    x = dpp_add<0x118>(x);  // row_shr:8
    x = dpp_add<0x142>(x);  // row_bcast15
    x = dpp_add<0x143>(x);  // row_bcast31 -> full sum in lane 63
    return x;
}

#define SUMS(xv, s, ss)                                                        \
    float s  = (xv.x + xv.y) + (xv.z + xv.w);                                  \
    float ss = fmaf(xv.x, xv.x, fmaf(xv.y, xv.y, fmaf(xv.z, xv.z, xv.w * xv.w)));

#define EMIT(xv, av, mean, rstd, dst) do {                                     \
    float ew, eb, o0, o1, o2, o3;                                              \
    ew = fmaf(av.x, w0.x, fmaf(av.y, w1.x, fmaf(av.z, w2.x, av.w * w3.x)));    \
    eb = fmaf(av.x, b0.x, fmaf(av.y, b1.x, fmaf(av.z, b2.x, av.w * b3.x)));    \
    o0 = fmaf((xv.x - mean) * rstd, ew, eb);                                   \
    ew = fmaf(av.x, w0.y, fmaf(av.y, w1.y, fmaf(av.z, w2.y, av.w * w3.y)));    \
    eb = fmaf(av.x, b0.y, fmaf(av.y, b1.y, fmaf(av.z, b2.y, av.w * b3.y)));    \
    o1 = fmaf((xv.y - mean) * rstd, ew, eb);                                   \
    ew = fmaf(av.x, w0.z, fmaf(av.y, w1.z, fmaf(av.z, w2.z, av.w * w3.z)));    \
    eb = fmaf(av.x, b0.z, fmaf(av.y, b1.z, fmaf(av.z, b2.z, av.w * b3.z)));    \
    o2 = fmaf((xv.z - mean) * rstd, ew, eb);                                   \
    ew = fmaf(av.x, w0.w, fmaf(av.y, w1.w, fmaf(av.z, w2.w, av.w * w3.w)));    \
    eb = fmaf(av.x, b0.w, fmaf(av.y, b1.w, fmaf(av.z, b2.w, av.w * b3.w)));    \
    o3 = fmaf((xv.w - mean) * rstd, ew, eb);                                   \
    st4_nt(dst, o0, o1, o2, o3);                                               \
} while (0)

__global__ __launch_bounds__(256, 4) void lns_kernel(
    const float* __restrict__ x,
    const float* __restrict__ alpha,
    const float* __restrict__ W,
    const float* __restrict__ Bias,
    float* __restrict__ out,
    int nrows)
{
    const int t  = threadIdx.x;
    const int h4 = t * 4;

    // Row-invariant W/b in registers (32 VGPRs).
    const float4 w0 = ld4(W + 0 * HS + h4);
    const float4 w1 = ld4(W + 1 * HS + h4);
    const float4 w2 = ld4(W + 2 * HS + h4);
    const float4 w3 = ld4(W + 3 * HS + h4);
    const float4 b0 = ld4(Bias + 0 * HS + h4);
    const float4 b1 = ld4(Bias + 1 * HS + h4);
    const float4 b2 = ld4(Bias + 2 * HS + h4);
    const float4 b3 = ld4(Bias + 3 * HS + h4);

    // red[parity][wave][j]: j=0 -> {s0,ss0,s1,ss1}, j=1 -> {s2,ss2,s3,ss3}
    __shared__ vfloat4 red[2][4][2];

    const int wv     = t >> 6;
    const int stride = gridDim.x * BPI;
    const int iters  = nrows / stride;  // exact: 32768 / 4096 = 8
    int row          = blockIdx.x * BPI;

    // Prologue: load iteration 0.
    size_t base = (size_t)row * HS + h4;
    float4 xc0 = ld4(x + base);
    float4 xc1 = ld4(x + base + HS);
    float4 xc2 = ld4(x + base + 2 * HS);
    float4 xc3 = ld4(x + base + 3 * HS);
    const float* ap = alpha + (size_t)row * 4;
    float4 aA = ld4(ap);
    float4 aB = ld4(ap + 4);
    float4 aC = ld4(ap + 8);
    float4 aD = ld4(ap + 12);

    for (int it = 0; it < iters; ++it, row += stride) {
        // Issue NEXT iteration's loads first: a full iteration of compute
        // (reduce + barrier + epilogue) covers their latency.
        float4 xn0, xn1, xn2, xn3, nA, nB, nC, nD;
        const bool more = (it + 1 < iters);
        if (more) {
            const size_t nb = (size_t)(row + stride) * HS + h4;
            xn0 = ld4(x + nb);
            xn1 = ld4(x + nb + HS);
            xn2 = ld4(x + nb + 2 * HS);
            xn3 = ld4(x + nb + 3 * HS);
            const float* np = alpha + (size_t)(row + stride) * 4;
            nA = ld4(np);
            nB = ld4(np + 4);
            nC = ld4(np + 8);
            nD = ld4(np + 12);
        }

        SUMS(xc0, s0, ss0);
        SUMS(xc1, s1, ss1);
        SUMS(xc2, s2, ss2);
        SUMS(xc3, s3, ss3);

        s0  = wave_sum_to_lane63(s0);
        ss0 = wave_sum_to_lane63(ss0);
        s1  = wave_sum_to_lane63(s1);
        ss1 = wave_sum_to_lane63(ss1);
        s2  = wave_sum_to_lane63(s2);
        ss2 = wave_sum_to_lane63(ss2);
        s3  = wave_sum_to_lane63(s3);
        ss3 = wave_sum_to_lane63(ss3);

        const int p = it & 1;
        if ((t & 63) == 63) {
            vfloat4 u = {s0, ss0, s1, ss1};
            vfloat4 v = {s2, ss2, s3, ss3};
            red[p][wv][0] = u;
            red[p][wv][1] = v;
        }
        __syncthreads();  // one barrier per 4 rows; parity buffer protects reuse

        const vfloat4 u0 = red[p][0][0], u1 = red[p][1][0], u2 = red[p][2][0], u3 = red[p][3][0];
        const vfloat4 v0 = red[p][0][1], v1 = red[p][1][1], v2 = red[p][2][1], v3 = red[p][3][1];
        s0  = (u0.x + u1.x) + (u2.x + u3.x);
        ss0 = (u0.y + u1.y) + (u2.y + u3.y);
        s1  = (u0.z + u1.z) + (u2.z + u3.z);
        ss1 = (u0.w + u1.w) + (u2.w + u3.w);
        s2  = (v0.x + v1.x) + (v2.x + v3.x);
        ss2 = (v0.y + v1.y) + (v2.y + v3.y);
        s3  = (v0.z + v1.z) + (v2.z + v3.z);
        ss3 = (v0.w + v1.w) + (v2.w + v3.w);

        const float mean0 = s0 * (1.0f / HS);
        const float rstd0 = rsqrtf(fmaf(-mean0, mean0, ss0 * (1.0f / HS)) + 1e-5f);
        const float mean1 = s1 * (1.0f / HS);
        const float rstd1 = rsqrtf(fmaf(-mean1, mean1, ss1 * (1.0f / HS)) + 1e-5f);
        const float mean2 = s2 * (1.0f / HS);
        const float rstd2 = rsqrtf(fmaf(-mean2, mean2, ss2 * (1.0f / HS)) + 1e-5f);
        const float mean3 = s3 * (1.0f / HS);
        const float rstd3 = rsqrtf(fmaf(-mean3, mean3, ss3 * (1.0f / HS)) + 1e-5f);

        base = (size_t)row * HS + h4;
        EMIT(xc0, aA, mean0, rstd0, out + base);
        EMIT(xc1, aB, mean1, rstd1, out + base + HS);
        EMIT(xc2, aC, mean2, rstd2, out + base + 2 * HS);
        EMIT(xc3, aD, mean3, rstd3, out + base + 3 * HS);

        xc0 = xn0; xc1 = xn1; xc2 = xn2; xc3 = xn3;
        aA = nA; aB = nB; aC = nC; aD = nD;
    }
}

extern "C" void kernel_launch(void* const* d_in, const int* in_sizes, int n_in,
                              void* d_out, int out_size, void* d_ws, size_t ws_size,
                              hipStream_t stream) {
    const float* x     = (const float*)d_in[0];
    const float* alpha = (const float*)d_in[1];
    const float* W     = (const float*)d_in[2];
    const float* Bias  = (const float*)d_in[3];
    float* out = (float*)d_out;

    const int nrows = in_sizes[0] / HS;  // 32768

    // 1024 blocks = 256 CUs x 4 blocks/CU (16 waves/CU at ~64 VGPR);
    // each block runs 8 iterations of 4 rows. 32768 = 1024*4*8 exactly.
    const int grid = 1024;
    lns_kernel<<<grid, 256, 0, stream>>>(x, alpha, W, Bias, out, nrows);
}